// Round 15
// baseline (306.558 us; speedup 1.0000x reference)
//
#include <hip/hip_runtime.h>
#include <math.h>

#define N_NODES 150000
#define N_EDGES 1200000
#define C 64
#define ACT 6
#define B_ROWS 25000   // N/ACT
#define GLOB 256
#define GOUT 10
#define H 32

#define NPAD 150016            // N rounded up (alignment)
#define SCAN_CHUNK 1024
#define NSCAN 147              // ceil(150000/1024)
#define MLP_BLOCKS 1563        // ceil(150000/96)

typedef short bf16x8 __attribute__((ext_vector_type(8)));
typedef float f32x4v __attribute__((ext_vector_type(4)));

// ---- bf16 helpers ----
__device__ __forceinline__ unsigned short f2bf(float f) {
    unsigned int u = __builtin_bit_cast(unsigned int, f);
    unsigned int r = (u + 0x7fffu + ((u >> 16) & 1u)) >> 16;   // RTNE
    return (unsigned short)r;
}
__device__ __forceinline__ unsigned int pack2bf(float a, float b) {
    return (unsigned int)f2bf(a) | ((unsigned int)f2bf(b) << 16);
}
__device__ __forceinline__ float bflo(unsigned int u) {
    return __builtin_bit_cast(float, u << 16);
}
__device__ __forceinline__ float bfhi(unsigned int u) {
    return __builtin_bit_cast(float, u & 0xffff0000u);
}
__device__ __forceinline__ float bf1(unsigned short us) {
    return __builtin_bit_cast(float, ((unsigned int)us) << 16);
}

// ---------------- degree histogram + per-edge rank ----------------
__global__ void degree_kernel(const int* __restrict__ dst, int* __restrict__ counts,
                              int* __restrict__ rank, int E) {
    int e = blockIdx.x * blockDim.x + threadIdx.x;
    if (e < E) rank[e] = atomicAdd(&counts[dst[e]], 1);
}

// ---------------- prefix scan (3 kernels) ----------------
__global__ void scan_block(const int* __restrict__ counts, int* __restrict__ rowptr,
                           int* __restrict__ bsum, int n) {
    __shared__ int lds[256];
    int base = blockIdx.x * SCAN_CHUNK;
    int t = threadIdx.x;
    int v[4]; int s = 0;
    #pragma unroll
    for (int i = 0; i < 4; ++i) {
        int idx = base + t * 4 + i;
        v[i] = (idx < n) ? counts[idx] : 0;
        s += v[i];
    }
    lds[t] = s; __syncthreads();
    for (int off = 1; off < 256; off <<= 1) {
        int x = (t >= off) ? lds[t - off] : 0;
        __syncthreads();
        lds[t] += x;
        __syncthreads();
    }
    int excl = lds[t] - s;
    if (t == 255) bsum[blockIdx.x] = lds[255];
    int run = excl;
    #pragma unroll
    for (int i = 0; i < 4; ++i) {
        int idx = base + t * 4 + i;
        if (idx < n) rowptr[idx] = run;
        run += v[i];
    }
}

__global__ void scan_sums(int* __restrict__ bsum, int nb) {
    __shared__ int lds[256];
    int t = threadIdx.x;
    int v = (t < nb) ? bsum[t] : 0;
    lds[t] = v; __syncthreads();
    for (int off = 1; off < 256; off <<= 1) {
        int x = (t >= off) ? lds[t - off] : 0;
        __syncthreads();
        lds[t] += x;
        __syncthreads();
    }
    if (t < nb) bsum[t] = lds[t] - v;   // exclusive
}

__global__ void scan_add(int* __restrict__ rowptr, const int* __restrict__ bsum,
                         const int* __restrict__ counts, float* __restrict__ dinv,
                         int n, int E) {
    int i = blockIdx.x * blockDim.x + threadIdx.x;
    if (i < n) {
        rowptr[i] += bsum[i >> 10];
        dinv[i] = rsqrtf((float)counts[i] + 1.0f);
    }
    if (i == n) rowptr[n] = E;
}

// ---------------- CSR fill (atomic-free; nontemporal scatter: no write-allocate) ----------------
__global__ void fill_csr(const int* __restrict__ src, const int* __restrict__ dst,
                         const int* __restrict__ rowptr, const int* __restrict__ rank,
                         int* __restrict__ csr, int E) {
    int e = blockIdx.x * blockDim.x + threadIdx.x;
    if (e >= E) return;
    int d = dst[e];
    __builtin_nontemporal_store(src[e], &csr[rowptr[d] + rank[e]]);
}

// ---------------- prep: cast weights to bf16 (state cast folded into conv_mfma) ----------------
__global__ void prep_cast(const float* __restrict__ convW, const float* __restrict__ gW1,
                          const float* __restrict__ l1W, const float* __restrict__ l2W,
                          unsigned short* __restrict__ wcb,   // [64*64]
                          unsigned short* __restrict__ w1b,   // [256*384]
                          unsigned short* __restrict__ w1p,   // [32*96] zero-padded
                          unsigned short* __restrict__ w2p) { // [32*32]
    int j = blockIdx.x * blockDim.x + threadIdx.x;
    if (j < 4096) {
        wcb[j] = f2bf(convW[j]);
    } else if (j < 4096 + 98304) {
        int k = j - 4096;
        w1b[k] = f2bf(gW1[k]);
    } else if (j < 4096 + 98304 + 3072) {
        int k = j - 4096 - 98304;
        int r = k / 96, c = k - r * 96;
        w1p[k] = (c < 74) ? f2bf(l1W[r * 74 + c]) : 0;
    } else if (j < 4096 + 98304 + 3072 + 1024) {
        int k = j - 4096 - 98304 - 3072;
        w2p[k] = f2bf(l2W[k]);
    }
}

// ---------------- conv via MFMA (fp32 state in, fused cast): hb, sb out ----------------
__global__ __launch_bounds__(256) void conv_mfma(
        const float* __restrict__ state,          // [N][64] fp32
        const unsigned short* __restrict__ wcb,   // [64][64] bf16
        const float* __restrict__ dinv,
        unsigned short* __restrict__ hb,
        unsigned short* __restrict__ sb, int n) {
    int wid  = threadIdx.x >> 6;
    int lane = threadIdx.x & 63;
    int quad = lane >> 4;
    int lm   = lane & 15;
    int row0 = (blockIdx.x * 4 + wid) * 16;
    if (row0 >= n) return;                        // n = 150000 = 16*9375: no partial waves

    const float* ap = state + (size_t)(row0 + lm) * 64 + quad * 8;
    float4 f0 = *(const float4*)ap;
    float4 f1 = *(const float4*)(ap + 4);
    float4 f2 = *(const float4*)(ap + 32);
    float4 f3 = *(const float4*)(ap + 36);
    uint4 p0 = make_uint4(pack2bf(f0.x, f0.y), pack2bf(f0.z, f0.w),
                          pack2bf(f1.x, f1.y), pack2bf(f1.z, f1.w));
    uint4 p1 = make_uint4(pack2bf(f2.x, f2.y), pack2bf(f2.z, f2.w),
                          pack2bf(f3.x, f3.y), pack2bf(f3.z, f3.w));
    *(uint4*)(sb + (size_t)(row0 + lm) * 64 + quad * 8)      = p0;
    *(uint4*)(sb + (size_t)(row0 + lm) * 64 + 32 + quad * 8) = p1;
    bf16x8 a0 = __builtin_bit_cast(bf16x8, p0);
    bf16x8 a1 = __builtin_bit_cast(bf16x8, p1);

    f32x4v acc[4];
    #pragma unroll
    for (int t = 0; t < 4; ++t) acc[t] = (f32x4v){0.f, 0.f, 0.f, 0.f};
    #pragma unroll
    for (int t = 0; t < 4; ++t) {
        const unsigned short* bp = wcb + (size_t)(t * 16 + lm) * 64 + quad * 8;
        bf16x8 b0 = *(const bf16x8*)bp;
        bf16x8 b1 = *(const bf16x8*)(bp + 32);
        acc[t] = __builtin_amdgcn_mfma_f32_16x16x32_bf16(a0, b0, acc[t], 0, 0, 0);
        acc[t] = __builtin_amdgcn_mfma_f32_16x16x32_bf16(a1, b1, acc[t], 0, 0, 0);
    }

    float dv[4];
    #pragma unroll
    for (int r = 0; r < 4; ++r) dv[r] = dinv[row0 + quad * 4 + r];
    #pragma unroll
    for (int t = 0; t < 4; ++t) {
        #pragma unroll
        for (int r = 0; r < 4; ++r) {
            int m = row0 + quad * 4 + r;
            hb[(size_t)m * 64 + t * 16 + lm] = f2bf(acc[t][r] * dv[r]);
        }
    }
}

// ---------------- gather: 8 nodes/wave, 8 lanes/node, no cross-lane reduction ----------------
__global__ void gather_fused(const int* __restrict__ rowptr, const int* __restrict__ csr,
                             const unsigned short* __restrict__ hb, const float* __restrict__ dinv,
                             const float* __restrict__ convb, const unsigned short* __restrict__ sb,
                             unsigned short* __restrict__ xb, int n, int E) {
    int wid  = threadIdx.x >> 6;
    int lane = threadIdx.x & 63;
    int g = lane >> 3;        // node slot within wave (0..7)
    int l = lane & 7;         // channel octet (8 bf16 per lane)
    int node = (blockIdx.x * 4 + wid) * 8 + g;
    bool valid = node < n;
    int nodec = valid ? node : (n - 1);
    int beg = rowptr[nodec], end = rowptr[nodec + 1];
    int deg = valid ? (end - beg) : 0;

    float acc[8] = {0.f, 0.f, 0.f, 0.f, 0.f, 0.f, 0.f, 0.f};
    int pidx = beg + l; if (pidx > E - 1) pidx = E - 1;
    int eid = csr[pidx];                        // prefetch up to 8 edge ids per node
    for (int i = 0; i < deg; ++i) {
        if ((i & 7) == 0 && i != 0) {
            int q = beg + i + l; if (q > E - 1) q = E - 1;
            eid = csr[q];
        }
        int s = __shfl(eid, (g << 3) + (i & 7), 64);   // broadcast within group
        uint4 u = *(const uint4*)(hb + (size_t)s * 64 + l * 8);
        acc[0] += bflo(u.x); acc[1] += bfhi(u.x);
        acc[2] += bflo(u.y); acc[3] += bfhi(u.y);
        acc[4] += bflo(u.z); acc[5] += bfhi(u.z);
        acc[6] += bflo(u.w); acc[7] += bfhi(u.w);
    }

    if (valid) {
        float dd = dinv[node];
        uint4 us = *(const uint4*)(hb + (size_t)node * 64 + l * 8);
        uint4 uv = *(const uint4*)(sb + (size_t)node * 64 + l * 8);
        float4 c0 = *(const float4*)(convb + l * 8);
        float4 c1 = *(const float4*)(convb + l * 8 + 4);
        float sf[8] = {bflo(us.x), bfhi(us.x), bflo(us.y), bfhi(us.y),
                       bflo(us.z), bfhi(us.z), bflo(us.w), bfhi(us.w)};
        float sv[8] = {bflo(uv.x), bfhi(uv.x), bflo(uv.y), bfhi(uv.y),
                       bflo(uv.z), bfhi(uv.z), bflo(uv.w), bfhi(uv.w)};
        float cb[8] = {c0.x, c0.y, c0.z, c0.w, c1.x, c1.y, c1.z, c1.w};
        float o[8];
        #pragma unroll
        for (int j = 0; j < 8; ++j) {
            float v = dd * (acc[j] + sf[j]) + cb[j];
            v = (v > 0.f) ? v : 0.f;
            o[j] = v + sv[j];
        }
        uint2 p0 = make_uint2(pack2bf(o[0], o[1]), pack2bf(o[2], o[3]));
        uint2 p1 = make_uint2(pack2bf(o[4], o[5]), pack2bf(o[6], o[7]));
        unsigned short* xp = xb + (size_t)node * 64 + l * 8;
        *(uint2*)xp       = p0;
        *(uint2*)(xp + 4) = p1;
    }
}

// ---------------- global branch layer 1 (MFMA bf16, LDS-staged B panel) ----------------
#define B_STRIDE 392
__global__ __launch_bounds__(512) void global_gemm1_mfma(
        const unsigned short* __restrict__ Ab,   // [25000][384] bf16
        const unsigned short* __restrict__ Wb,   // [256][384] bf16
        const float* __restrict__ bias,          // gb1
        unsigned short* __restrict__ y1b, int M) {
    __shared__ unsigned short Blds[64 * B_STRIDE];   // 50176 B

    int tid  = threadIdx.x;
    int mb   = blockIdx.x >> 2;
    int q    = blockIdx.x & 3;
    int col0 = q * 64;

    #pragma unroll
    for (int i = 0; i < 6; ++i) {
        int seg = i * 512 + tid;
        int row = seg / 48;
        int off = (seg - row * 48) * 8;
        uint4 v = *(const uint4*)(Wb + (size_t)(col0 + row) * 384 + off);
        *(uint4*)(&Blds[row * B_STRIDE + off]) = v;
    }
    __syncthreads();

    int wave = tid >> 6;
    int lane = tid & 63;
    int quad = lane >> 4;
    int lm   = lane & 15;
    int row0 = mb * 128 + wave * 16;

    int arow = row0 + lm;
    if (arow >= M) arow = M - 1;
    const unsigned short* ap = Ab + (size_t)arow * 384 + quad * 8;

    bf16x8 af[12];
    #pragma unroll
    for (int ks = 0; ks < 12; ++ks) af[ks] = *(const bf16x8*)(ap + ks * 32);

    f32x4v acc[4];
    #pragma unroll
    for (int t = 0; t < 4; ++t) acc[t] = (f32x4v){0.f, 0.f, 0.f, 0.f};

    #pragma unroll
    for (int ks = 0; ks < 12; ++ks) {
        #pragma unroll
        for (int t = 0; t < 4; ++t) {
            bf16x8 bfr = *(const bf16x8*)(&Blds[(t * 16 + lm) * B_STRIDE + ks * 32 + quad * 8]);
            acc[t] = __builtin_amdgcn_mfma_f32_16x16x32_bf16(af[ks], bfr, acc[t], 0, 0, 0);
        }
    }

    #pragma unroll
    for (int t = 0; t < 4; ++t) {
        int nn = col0 + t * 16 + lm;
        float bv = bias[nn];
        #pragma unroll
        for (int r = 0; r < 4; ++r) {
            int m = row0 + quad * 4 + r;
            if (m < M) {
                float v = acc[t][r] + bv;
                v = (v > 0.f) ? v : 0.01f * v;
                y1b[(size_t)m * 256 + nn] = f2bf(v);
            }
        }
    }
}

// ---------------- global branch layer 2: xgb = bf16 [B][16] (zero-padded) ----------------
__global__ void global_gemm2(const unsigned short* __restrict__ y1b, const float* __restrict__ W2,
                             const float* __restrict__ b2, unsigned short* __restrict__ xgb, int B) {
    int wave = (blockIdx.x * blockDim.x + threadIdx.x) >> 6;
    int lane = threadIdx.x & 63;
    if (wave >= B) return;
    const unsigned short* yr = y1b + (size_t)wave * 256;
    float yv[4];
    #pragma unroll
    for (int j = 0; j < 4; ++j) yv[j] = bf1(yr[lane + 64 * j]);
    float res[10];
    #pragma unroll
    for (int o = 0; o < 10; ++o) {
        const float* w = W2 + o * 256;
        float p = 0.f;
        #pragma unroll
        for (int j = 0; j < 4; ++j) p += yv[j] * w[lane + 64 * j];
        #pragma unroll
        for (int off = 32; off > 0; off >>= 1) p += __shfl_down(p, off, 64);
        res[o] = p;
    }
    if (lane == 0) {
        float v[10];
        #pragma unroll
        for (int o = 0; o < 10; ++o) {
            float t = res[o] + b2[o];
            v[o] = (t > 0.f) ? t : 0.01f * t;
        }
        uint4 pa = make_uint4(pack2bf(v[0], v[1]), pack2bf(v[2], v[3]),
                              pack2bf(v[4], v[5]), pack2bf(v[6], v[7]));
        uint4 pb = make_uint4(pack2bf(v[8], v[9]), 0u, 0u, 0u);
        unsigned short* xp = xgb + (size_t)wave * 16;
        *(uint4*)xp       = pa;
        *(uint4*)(xp + 8) = pb;
    }
}

// ---------------- final MLP via MFMA: 6 waves/block, 1 tile (16 nodes) per wave ----------------
#define Y1_STRIDE 40
__global__ __launch_bounds__(384) void mlp_mfma(
        const unsigned short* __restrict__ xb,    // [N][64] bf16
        const unsigned short* __restrict__ xgb,   // [B][16] bf16 zero-padded
        const unsigned short* __restrict__ w1p,   // [32][96] bf16 zero-padded
        const unsigned short* __restrict__ w2p,   // [32][32] bf16
        const float* __restrict__ l1b, const float* __restrict__ l2b,
        const float* __restrict__ l3W, const float* __restrict__ l3b,
        float* __restrict__ out, float* __restrict__ partial, int n) {
    __shared__ unsigned short y1L[6][16 * Y1_STRIDE];
    __shared__ float conc[96];
    __shared__ float wsum[6];

    int wid  = threadIdx.x >> 6;
    int lane = threadIdx.x & 63;
    int quad = lane >> 4;
    int lm   = lane & 15;
    int nbase = blockIdx.x * 96;
    int node  = nbase + wid * 16 + lm;
    int nodec = (node < n) ? node : (n - 1);      // clamp loads; stores predicated

    bf16x8 b1[2][3];
    #pragma unroll
    for (int t2 = 0; t2 < 2; ++t2)
        #pragma unroll
        for (int ks = 0; ks < 3; ++ks)
            b1[t2][ks] = *(const bf16x8*)(w1p + (t2 * 16 + lm) * 96 + ks * 32 + quad * 8);
    bf16x8 b2f[2];
    #pragma unroll
    for (int t2 = 0; t2 < 2; ++t2)
        b2f[t2] = *(const bf16x8*)(w2p + (t2 * 16 + lm) * 32 + quad * 8);

    float bias1a = l1b[lm],      bias1b = l1b[16 + lm];
    float bias2a = l2b[lm],      bias2b = l2b[16 + lm];
    float w3a    = l3W[lm],      w3b    = l3W[16 + lm];
    float b3     = l3b[0];

    bf16x8 a0 = *(const bf16x8*)(xb + (size_t)nodec * 64 + quad * 8);
    bf16x8 a1 = *(const bf16x8*)(xb + (size_t)nodec * 64 + 32 + quad * 8);
    bf16x8 a2 = (bf16x8){0, 0, 0, 0, 0, 0, 0, 0};
    if (quad < 2) a2 = *(const bf16x8*)(xgb + (size_t)(nodec / 6) * 16 + quad * 8);

    f32x4v acc0 = (f32x4v){0.f, 0.f, 0.f, 0.f};
    f32x4v acc1 = acc0;
    acc0 = __builtin_amdgcn_mfma_f32_16x16x32_bf16(a0, b1[0][0], acc0, 0, 0, 0);
    acc1 = __builtin_amdgcn_mfma_f32_16x16x32_bf16(a0, b1[1][0], acc1, 0, 0, 0);
    acc0 = __builtin_amdgcn_mfma_f32_16x16x32_bf16(a1, b1[0][1], acc0, 0, 0, 0);
    acc1 = __builtin_amdgcn_mfma_f32_16x16x32_bf16(a1, b1[1][1], acc1, 0, 0, 0);
    acc0 = __builtin_amdgcn_mfma_f32_16x16x32_bf16(a2, b1[0][2], acc0, 0, 0, 0);
    acc1 = __builtin_amdgcn_mfma_f32_16x16x32_bf16(a2, b1[1][2], acc1, 0, 0, 0);

    unsigned short* myY = y1L[wid];
    #pragma unroll
    for (int r = 0; r < 4; ++r) {
        float v0 = acc0[r] + bias1a;
        float v1 = acc1[r] + bias1b;
        v0 = (v0 > 0.f) ? v0 : 0.01f * v0;
        v1 = (v1 > 0.f) ? v1 : 0.01f * v1;
        myY[(quad * 4 + r) * Y1_STRIDE + lm]      = f2bf(v0);
        myY[(quad * 4 + r) * Y1_STRIDE + 16 + lm] = f2bf(v1);
    }
    bf16x8 a2f = *(const bf16x8*)(myY + lm * Y1_STRIDE + quad * 8);
    f32x4v acc20 = (f32x4v){0.f, 0.f, 0.f, 0.f};
    f32x4v acc21 = acc20;
    acc20 = __builtin_amdgcn_mfma_f32_16x16x32_bf16(a2f, b2f[0], acc20, 0, 0, 0);
    acc21 = __builtin_amdgcn_mfma_f32_16x16x32_bf16(a2f, b2f[1], acc21, 0, 0, 0);

    float part[4];
    #pragma unroll
    for (int r = 0; r < 4; ++r) {
        float y2a = acc20[r] + bias2a;
        float y2b = acc21[r] + bias2b;
        y2a = (y2a > 0.f) ? y2a : 0.01f * y2a;
        y2b = (y2b > 0.f) ? y2b : 0.01f * y2b;
        part[r] = y2a * w3a + y2b * w3b;
    }
    #pragma unroll
    for (int st = 1; st < 16; st <<= 1) {
        #pragma unroll
        for (int r = 0; r < 4; ++r) part[r] += __shfl_xor(part[r], st, 64);
    }
    if (lm == 0) {
        #pragma unroll
        for (int r = 0; r < 4; ++r) {
            float a3 = part[r] + b3;
            conc[wid * 16 + quad * 4 + r] = (a3 > 20.f) ? a3 : log1pf(expf(a3));
        }
    }
    __syncthreads();

    int tid = threadIdx.x;
    float myabs = 0.f;
    if (tid < 96) {
        int gnode = nbase + tid;
        if (gnode < n) {
            int g0 = (tid / 6) * 6;
            float s = 0.f;
            #pragma unroll
            for (int i = 0; i < 6; ++i) s += conc[g0 + i];
            float c = conc[tid];
            out[gnode] = c / (s + 1e-20f);
            myabs = fabsf(c);
        }
    }
    #pragma unroll
    for (int off = 32; off > 0; off >>= 1) myabs += __shfl_down(myabs, off, 64);
    if (lane == 0) wsum[wid] = myabs;
    __syncthreads();
    if (tid == 0)
        partial[blockIdx.x] = wsum[0] + wsum[1] + wsum[2] + wsum[3] + wsum[4] + wsum[5];
}

// ---------------- final reduction of per-block partials ----------------
__global__ void reduce_reg(const float* __restrict__ partial, float* __restrict__ regptr, int nb) {
    __shared__ float wsum[4];
    int tid = threadIdx.x;
    float s = 0.f;
    for (int i = tid; i < nb; i += 256) s += partial[i];
    #pragma unroll
    for (int off = 32; off > 0; off >>= 1) s += __shfl_down(s, off, 64);
    if ((tid & 63) == 0) wsum[tid >> 6] = s;
    __syncthreads();
    if (tid == 0)
        *regptr = (wsum[0] + wsum[1] + wsum[2] + wsum[3]) * (1.0f / (float)N_NODES);
}

extern "C" void kernel_launch(void* const* d_in, const int* in_sizes, int n_in,
                              void* d_out, int out_size, void* d_ws, size_t ws_size,
                              hipStream_t stream) {
    const float* state = (const float*)d_in[0];
    const int*   ei    = (const int*)d_in[1];
    const float* convW = (const float*)d_in[2];
    const float* convb = (const float*)d_in[3];
    const float* gW1   = (const float*)d_in[4];
    const float* gb1   = (const float*)d_in[5];
    const float* gW2   = (const float*)d_in[6];
    const float* gb2   = (const float*)d_in[7];
    const float* l1W   = (const float*)d_in[8];
    const float* l1b   = (const float*)d_in[9];
    const float* l2W   = (const float*)d_in[10];
    const float* l2b   = (const float*)d_in[11];
    const float* l3W   = (const float*)d_in[12];
    const float* l3b   = (const float*)d_in[13];

    const int n = N_NODES, E = N_EDGES, B = B_ROWS;
    const int* src = ei;
    const int* dst = ei + E;

    // ---- workspace layout ----
    char* w = (char*)d_ws;
    int*   counts = (int*)w;                 w += NPAD * 4;
    int*   rank   = (int*)w;                 w += (size_t)E * 4;
    int*   rowptr = (int*)w;                 w += NPAD * 4;
    int*   bsum   = (int*)w;                 w += 256 * 4;
    float* dinv   = (float*)w;               w += NPAD * 4;
    int*   csr    = (int*)w;                 w += (size_t)E * 4;
    float* hregion= (float*)w;               w += (size_t)n * 64 * 4; // 38.4 MB
    unsigned short* xb = (unsigned short*)w; w += (size_t)n * 64 * 2; // 19.2 MB
    unsigned short* w1b = (unsigned short*)w; w += 98304 * 2;
    unsigned short* w1p = (unsigned short*)w; w += 3072 * 2;
    unsigned short* w2p = (unsigned short*)w; w += 1024 * 2;
    unsigned short* wcb = (unsigned short*)w; w += 4096 * 2;
    float* partial = (float*)w;              w += MLP_BLOCKS * 4;
    // hregion phases:
    //   phase 1: hb = [0..19.2MB) bf16 h*dinv ; sb = [19.2..38.4MB) bf16 state
    //   phase 2: y1b = [0..12.8MB) bf16 y1 (hb dead) ; xgb = [12.8..13.6MB) bf16 [B][16]
    unsigned short* hb  = (unsigned short*)hregion;
    unsigned short* sb  = (unsigned short*)(hregion + 4800000);
    unsigned short* y1b = (unsigned short*)hregion;
    unsigned short* xgb = (unsigned short*)(hregion + 3200000);

    float* out    = (float*)d_out;
    float* regptr = out + n;

    hipMemsetAsync(counts, 0, NPAD * 4, stream);

    degree_kernel<<<(E + 255) / 256, 256, 0, stream>>>(dst, counts, rank, E);
    scan_block<<<NSCAN, 256, 0, stream>>>(counts, rowptr, bsum, n);
    scan_sums<<<1, 256, 0, stream>>>(bsum, NSCAN);
    scan_add<<<(n + 256) / 256, 256, 0, stream>>>(rowptr, bsum, counts, dinv, n, E);
    fill_csr<<<(E + 255) / 256, 256, 0, stream>>>(src, dst, rowptr, rank, csr, E);
    prep_cast<<<(4096 + 98304 + 3072 + 1024 + 255) / 256, 256, 0, stream>>>(
        convW, gW1, l1W, l2W, wcb, w1b, w1p, w2p);
    conv_mfma<<<(9375 + 3) / 4, 256, 0, stream>>>(state, wcb, dinv, hb, sb, n);
    gather_fused<<<(n + 31) / 32, 256, 0, stream>>>(rowptr, csr, hb, dinv, convb, sb, xb, n, E);
    global_gemm1_mfma<<<196 * 4, 512, 0, stream>>>(sb, w1b, gb1, y1b, B);
    global_gemm2<<<(B * 64 + 255) / 256, 256, 0, stream>>>(y1b, gW2, gb2, xgb, B);
    mlp_mfma<<<MLP_BLOCKS, 384, 0, stream>>>(xb, xgb, w1p, w2p, l1b, l2b, l3W, l3b,
                                             out, partial, n);
    reduce_reg<<<1, 256, 0, stream>>>(partial, regptr, MLP_BLOCKS);
}

// Round 17
// 282.525 us; speedup vs baseline: 1.0851x; 1.0851x over previous
//
#include <hip/hip_runtime.h>
#include <math.h>

#define N_NODES 150000
#define N_EDGES 1200000
#define C 64
#define ACT 6
#define B_ROWS 25000   // N/ACT
#define GLOB 256
#define GOUT 10
#define H 32

#define NPAD 150016            // N rounded up (alignment)
#define SCAN_CHUNK 1024
#define NSCAN 147              // ceil(150000/1024)
#define MLP_BLOCKS 1563        // ceil(150000/96)

#define PREP_BLOCKS 416        // 106496/256
#define DEGREE_BLOCKS 4688     // ceil(1.2M/256)
#define CONV_BLOCKS 2344       // ceil(9375/4)
#define FILL_BLOCKS 4688
#define GEMM1_BLOCKS 784       // 196*4
#define GATHER_BLOCKS 2344     // ceil(150000/64)

typedef short bf16x8 __attribute__((ext_vector_type(8)));
typedef float f32x4v __attribute__((ext_vector_type(4)));

// ---- bf16 helpers ----
__device__ __forceinline__ unsigned short f2bf(float f) {
    unsigned int u = __builtin_bit_cast(unsigned int, f);
    unsigned int r = (u + 0x7fffu + ((u >> 16) & 1u)) >> 16;   // RTNE
    return (unsigned short)r;
}
__device__ __forceinline__ unsigned int pack2bf(float a, float b) {
    return (unsigned int)f2bf(a) | ((unsigned int)f2bf(b) << 16);
}
__device__ __forceinline__ float bflo(unsigned int u) {
    return __builtin_bit_cast(float, u << 16);
}
__device__ __forceinline__ float bfhi(unsigned int u) {
    return __builtin_bit_cast(float, u & 0xffff0000u);
}
__device__ __forceinline__ float bf1(unsigned short us) {
    return __builtin_bit_cast(float, ((unsigned int)us) << 16);
}

// ================ k1: prep (weights->bf16) || degree histogram+rank ================
__global__ __launch_bounds__(256) void k1_prep_degree(
        const int* __restrict__ dst, int* __restrict__ counts, int* __restrict__ rank,
        const float* __restrict__ convW, const float* __restrict__ gW1,
        const float* __restrict__ l1W, const float* __restrict__ l2W,
        unsigned short* __restrict__ wcb, unsigned short* __restrict__ w1b,
        unsigned short* __restrict__ w1p, unsigned short* __restrict__ w2p, int E) {
    int bi = blockIdx.x;
    if (bi < PREP_BLOCKS) {
        int j = bi * 256 + threadIdx.x;
        if (j < 4096) {
            wcb[j] = f2bf(convW[j]);
        } else if (j < 4096 + 98304) {
            int k = j - 4096;
            w1b[k] = f2bf(gW1[k]);
        } else if (j < 4096 + 98304 + 3072) {
            int k = j - 4096 - 98304;
            int r = k / 96, c = k - r * 96;
            w1p[k] = (c < 74) ? f2bf(l1W[r * 74 + c]) : 0;
        } else if (j < 106496) {
            int k = j - 4096 - 98304 - 3072;
            w2p[k] = f2bf(l2W[k]);
        }
        return;
    }
    int e = (bi - PREP_BLOCKS) * 256 + threadIdx.x;
    if (e < E) rank[e] = atomicAdd(&counts[dst[e]], 1);
}

// ---------------- prefix scan (3 kernels) ----------------
__global__ void scan_block(const int* __restrict__ counts, int* __restrict__ rowptr,
                           int* __restrict__ bsum, int n) {
    __shared__ int lds[256];
    int base = blockIdx.x * SCAN_CHUNK;
    int t = threadIdx.x;
    int v[4]; int s = 0;
    #pragma unroll
    for (int i = 0; i < 4; ++i) {
        int idx = base + t * 4 + i;
        v[i] = (idx < n) ? counts[idx] : 0;
        s += v[i];
    }
    lds[t] = s; __syncthreads();
    for (int off = 1; off < 256; off <<= 1) {
        int x = (t >= off) ? lds[t - off] : 0;
        __syncthreads();
        lds[t] += x;
        __syncthreads();
    }
    int excl = lds[t] - s;
    if (t == 255) bsum[blockIdx.x] = lds[255];
    int run = excl;
    #pragma unroll
    for (int i = 0; i < 4; ++i) {
        int idx = base + t * 4 + i;
        if (idx < n) rowptr[idx] = run;
        run += v[i];
    }
}

__global__ void scan_sums(int* __restrict__ bsum, int nb) {
    __shared__ int lds[256];
    int t = threadIdx.x;
    int v = (t < nb) ? bsum[t] : 0;
    lds[t] = v; __syncthreads();
    for (int off = 1; off < 256; off <<= 1) {
        int x = (t >= off) ? lds[t - off] : 0;
        __syncthreads();
        lds[t] += x;
        __syncthreads();
    }
    if (t < nb) bsum[t] = lds[t] - v;   // exclusive
}

__global__ void scan_add(int* __restrict__ rowptr, const int* __restrict__ bsum,
                         const int* __restrict__ counts, float* __restrict__ dinv,
                         int n, int E) {
    int i = blockIdx.x * blockDim.x + threadIdx.x;
    if (i < n) {
        rowptr[i] += bsum[i >> 10];
        dinv[i] = rsqrtf((float)counts[i] + 1.0f);
    }
    if (i == n) rowptr[n] = E;
}

// ================ k2: conv (MFMA, fused fp32->bf16 cast) || CSR fill ================
__global__ __launch_bounds__(256) void k2_conv_fill(
        const float* __restrict__ state, const unsigned short* __restrict__ wcb,
        const float* __restrict__ dinv,
        unsigned short* __restrict__ hb, unsigned short* __restrict__ sb,
        const int* __restrict__ src, const int* __restrict__ dst,
        const int* __restrict__ rowptr, const int* __restrict__ rank,
        int* __restrict__ csr, int n, int E) {
    int bi = blockIdx.x;
    if (bi < CONV_BLOCKS) {
        int wid  = threadIdx.x >> 6;
        int lane = threadIdx.x & 63;
        int quad = lane >> 4;
        int lm   = lane & 15;
        int row0 = (bi * 4 + wid) * 16;
        if (row0 >= n) return;                    // n = 150000 = 16*9375

        const float* ap = state + (size_t)(row0 + lm) * 64 + quad * 8;
        float4 f0 = *(const float4*)ap;
        float4 f1 = *(const float4*)(ap + 4);
        float4 f2 = *(const float4*)(ap + 32);
        float4 f3 = *(const float4*)(ap + 36);
        uint4 p0 = make_uint4(pack2bf(f0.x, f0.y), pack2bf(f0.z, f0.w),
                              pack2bf(f1.x, f1.y), pack2bf(f1.z, f1.w));
        uint4 p1 = make_uint4(pack2bf(f2.x, f2.y), pack2bf(f2.z, f2.w),
                              pack2bf(f3.x, f3.y), pack2bf(f3.z, f3.w));
        *(uint4*)(sb + (size_t)(row0 + lm) * 64 + quad * 8)      = p0;
        *(uint4*)(sb + (size_t)(row0 + lm) * 64 + 32 + quad * 8) = p1;
        bf16x8 a0 = __builtin_bit_cast(bf16x8, p0);
        bf16x8 a1 = __builtin_bit_cast(bf16x8, p1);

        f32x4v acc[4];
        #pragma unroll
        for (int t = 0; t < 4; ++t) acc[t] = (f32x4v){0.f, 0.f, 0.f, 0.f};
        #pragma unroll
        for (int t = 0; t < 4; ++t) {
            const unsigned short* bp = wcb + (size_t)(t * 16 + lm) * 64 + quad * 8;
            bf16x8 b0 = *(const bf16x8*)bp;
            bf16x8 b1 = *(const bf16x8*)(bp + 32);
            acc[t] = __builtin_amdgcn_mfma_f32_16x16x32_bf16(a0, b0, acc[t], 0, 0, 0);
            acc[t] = __builtin_amdgcn_mfma_f32_16x16x32_bf16(a1, b1, acc[t], 0, 0, 0);
        }

        float dv[4];
        #pragma unroll
        for (int r = 0; r < 4; ++r) dv[r] = dinv[row0 + quad * 4 + r];
        #pragma unroll
        for (int t = 0; t < 4; ++t) {
            #pragma unroll
            for (int r = 0; r < 4; ++r) {
                int m = row0 + quad * 4 + r;
                hb[(size_t)m * 64 + t * 16 + lm] = f2bf(acc[t][r] * dv[r]);
            }
        }
        return;
    }
    int e = (bi - CONV_BLOCKS) * 256 + threadIdx.x;
    if (e < E) {
        int d = dst[e];
        csr[rowptr[d] + rank[e]] = src[e];
    }
}

// ================ k3: gemm1 (MFMA, LDS B panel) || gather (8 waves/block) ================
// y1b is a DEDICATED buffer (must NOT alias hb: gather reads hb concurrently).
#define B_STRIDE 392
__global__ __launch_bounds__(512) void k3_gemm1_gather(
        const unsigned short* __restrict__ Ab,   // sb [25000][384] bf16
        const unsigned short* __restrict__ Wb,   // w1b [256][384] bf16
        const float* __restrict__ bias,          // gb1
        unsigned short* __restrict__ y1b, int M,
        const int* __restrict__ rowptr, const int* __restrict__ csr,
        const unsigned short* __restrict__ hb, const float* __restrict__ dinv,
        const float* __restrict__ convb,
        unsigned short* __restrict__ xb, int n, int E) {
    __shared__ unsigned short Blds[64 * B_STRIDE];   // 50176 B (gemm1 branch only)

    int bi  = blockIdx.x;
    int tid = threadIdx.x;
    if (bi < GEMM1_BLOCKS) {
        int mb   = bi >> 2;
        int q    = bi & 3;
        int col0 = q * 64;

        #pragma unroll
        for (int i = 0; i < 6; ++i) {
            int seg = i * 512 + tid;
            int row = seg / 48;
            int off = (seg - row * 48) * 8;
            uint4 v = *(const uint4*)(Wb + (size_t)(col0 + row) * 384 + off);
            *(uint4*)(&Blds[row * B_STRIDE + off]) = v;
        }
        __syncthreads();

        int wave = tid >> 6;
        int lane = tid & 63;
        int quad = lane >> 4;
        int lm   = lane & 15;
        int row0 = mb * 128 + wave * 16;

        int arow = row0 + lm;
        if (arow >= M) arow = M - 1;
        const unsigned short* ap = Ab + (size_t)arow * 384 + quad * 8;

        bf16x8 af[12];
        #pragma unroll
        for (int ks = 0; ks < 12; ++ks) af[ks] = *(const bf16x8*)(ap + ks * 32);

        f32x4v acc[4];
        #pragma unroll
        for (int t = 0; t < 4; ++t) acc[t] = (f32x4v){0.f, 0.f, 0.f, 0.f};

        #pragma unroll
        for (int ks = 0; ks < 12; ++ks) {
            #pragma unroll
            for (int t = 0; t < 4; ++t) {
                bf16x8 bfr = *(const bf16x8*)(&Blds[(t * 16 + lm) * B_STRIDE + ks * 32 + quad * 8]);
                acc[t] = __builtin_amdgcn_mfma_f32_16x16x32_bf16(af[ks], bfr, acc[t], 0, 0, 0);
            }
        }

        #pragma unroll
        for (int t = 0; t < 4; ++t) {
            int nn = col0 + t * 16 + lm;
            float bv = bias[nn];
            #pragma unroll
            for (int r = 0; r < 4; ++r) {
                int m = row0 + quad * 4 + r;
                if (m < M) {
                    float v = acc[t][r] + bv;
                    v = (v > 0.f) ? v : 0.01f * v;
                    y1b[(size_t)m * 256 + nn] = f2bf(v);
                }
            }
        }
        return;
    }

    // ---- gather branch: 8 waves/block, 8 nodes/wave, 8 lanes/node ----
    int gb   = bi - GEMM1_BLOCKS;
    int wid  = tid >> 6;
    int lane = tid & 63;
    int g = lane >> 3;
    int l = lane & 7;
    int node = (gb * 8 + wid) * 8 + g;
    bool valid = node < n;
    int nodec = valid ? node : (n - 1);
    int beg = rowptr[nodec], end = rowptr[nodec + 1];
    int deg = valid ? (end - beg) : 0;

    float acc[8] = {0.f, 0.f, 0.f, 0.f, 0.f, 0.f, 0.f, 0.f};
    int pidx = beg + l; if (pidx > E - 1) pidx = E - 1;
    int eid = csr[pidx];
    for (int i = 0; i < deg; ++i) {
        if ((i & 7) == 0 && i != 0) {
            int q2 = beg + i + l; if (q2 > E - 1) q2 = E - 1;
            eid = csr[q2];
        }
        int s = __shfl(eid, (g << 3) + (i & 7), 64);
        uint4 u = *(const uint4*)(hb + (size_t)s * 64 + l * 8);
        acc[0] += bflo(u.x); acc[1] += bfhi(u.x);
        acc[2] += bflo(u.y); acc[3] += bfhi(u.y);
        acc[4] += bflo(u.z); acc[5] += bfhi(u.z);
        acc[6] += bflo(u.w); acc[7] += bfhi(u.w);
    }

    if (valid) {
        float dd = dinv[node];
        uint4 us = *(const uint4*)(hb + (size_t)node * 64 + l * 8);
        uint4 uv = *(const uint4*)(Ab + (size_t)node * 64 + l * 8);   // sb
        float4 c0 = *(const float4*)(convb + l * 8);
        float4 c1 = *(const float4*)(convb + l * 8 + 4);
        float sf[8] = {bflo(us.x), bfhi(us.x), bflo(us.y), bfhi(us.y),
                       bflo(us.z), bfhi(us.z), bflo(us.w), bfhi(us.w)};
        float sv[8] = {bflo(uv.x), bfhi(uv.x), bflo(uv.y), bfhi(uv.y),
                       bflo(uv.z), bfhi(uv.z), bflo(uv.w), bfhi(uv.w)};
        float cb[8] = {c0.x, c0.y, c0.z, c0.w, c1.x, c1.y, c1.z, c1.w};
        float o[8];
        #pragma unroll
        for (int j = 0; j < 8; ++j) {
            float v = dd * (acc[j] + sf[j]) + cb[j];
            v = (v > 0.f) ? v : 0.f;
            o[j] = v + sv[j];
        }
        uint2 p0 = make_uint2(pack2bf(o[0], o[1]), pack2bf(o[2], o[3]));
        uint2 p1 = make_uint2(pack2bf(o[4], o[5]), pack2bf(o[6], o[7]));
        unsigned short* xp = xb + (size_t)node * 64 + l * 8;
        *(uint2*)xp       = p0;
        *(uint2*)(xp + 4) = p1;
    }
}

// ---------------- global branch layer 2: xgb = bf16 [B][16] (zero-padded) ----------------
__global__ void global_gemm2(const unsigned short* __restrict__ y1b, const float* __restrict__ W2,
                             const float* __restrict__ b2, unsigned short* __restrict__ xgb, int B) {
    int wave = (blockIdx.x * blockDim.x + threadIdx.x) >> 6;
    int lane = threadIdx.x & 63;
    if (wave >= B) return;
    const unsigned short* yr = y1b + (size_t)wave * 256;
    float yv[4];
    #pragma unroll
    for (int j = 0; j < 4; ++j) yv[j] = bf1(yr[lane + 64 * j]);
    float res[10];
    #pragma unroll
    for (int o = 0; o < 10; ++o) {
        const float* w = W2 + o * 256;
        float p = 0.f;
        #pragma unroll
        for (int j = 0; j < 4; ++j) p += yv[j] * w[lane + 64 * j];
        #pragma unroll
        for (int off = 32; off > 0; off >>= 1) p += __shfl_down(p, off, 64);
        res[o] = p;
    }
    if (lane == 0) {
        float v[10];
        #pragma unroll
        for (int o = 0; o < 10; ++o) {
            float t = res[o] + b2[o];
            v[o] = (t > 0.f) ? t : 0.01f * t;
        }
        uint4 pa = make_uint4(pack2bf(v[0], v[1]), pack2bf(v[2], v[3]),
                              pack2bf(v[4], v[5]), pack2bf(v[6], v[7]));
        uint4 pb = make_uint4(pack2bf(v[8], v[9]), 0u, 0u, 0u);
        unsigned short* xp = xgb + (size_t)wave * 16;
        *(uint4*)xp       = pa;
        *(uint4*)(xp + 8) = pb;
    }
}

// ---------------- final MLP via MFMA: 6 waves/block, 1 tile (16 nodes) per wave ----------------
#define Y1_STRIDE 40
__global__ __launch_bounds__(384) void mlp_mfma(
        const unsigned short* __restrict__ xb,    // [N][64] bf16
        const unsigned short* __restrict__ xgb,   // [B][16] bf16 zero-padded
        const unsigned short* __restrict__ w1p,   // [32][96] bf16 zero-padded
        const unsigned short* __restrict__ w2p,   // [32][32] bf16
        const float* __restrict__ l1b, const float* __restrict__ l2b,
        const float* __restrict__ l3W, const float* __restrict__ l3b,
        float* __restrict__ out, float* __restrict__ partial, int n) {
    __shared__ unsigned short y1L[6][16 * Y1_STRIDE];
    __shared__ float conc[96];
    __shared__ float wsum[6];

    int wid  = threadIdx.x >> 6;
    int lane = threadIdx.x & 63;
    int quad = lane >> 4;
    int lm   = lane & 15;
    int nbase = blockIdx.x * 96;
    int node  = nbase + wid * 16 + lm;
    int nodec = (node < n) ? node : (n - 1);      // clamp loads; stores predicated

    bf16x8 b1[2][3];
    #pragma unroll
    for (int t2 = 0; t2 < 2; ++t2)
        #pragma unroll
        for (int ks = 0; ks < 3; ++ks)
            b1[t2][ks] = *(const bf16x8*)(w1p + (t2 * 16 + lm) * 96 + ks * 32 + quad * 8);
    bf16x8 b2f[2];
    #pragma unroll
    for (int t2 = 0; t2 < 2; ++t2)
        b2f[t2] = *(const bf16x8*)(w2p + (t2 * 16 + lm) * 32 + quad * 8);

    float bias1a = l1b[lm],      bias1b = l1b[16 + lm];
    float bias2a = l2b[lm],      bias2b = l2b[16 + lm];
    float w3a    = l3W[lm],      w3b    = l3W[16 + lm];
    float b3     = l3b[0];

    bf16x8 a0 = *(const bf16x8*)(xb + (size_t)nodec * 64 + quad * 8);
    bf16x8 a1 = *(const bf16x8*)(xb + (size_t)nodec * 64 + 32 + quad * 8);
    bf16x8 a2 = (bf16x8){0, 0, 0, 0, 0, 0, 0, 0};
    if (quad < 2) a2 = *(const bf16x8*)(xgb + (size_t)(nodec / 6) * 16 + quad * 8);

    f32x4v acc0 = (f32x4v){0.f, 0.f, 0.f, 0.f};
    f32x4v acc1 = acc0;
    acc0 = __builtin_amdgcn_mfma_f32_16x16x32_bf16(a0, b1[0][0], acc0, 0, 0, 0);
    acc1 = __builtin_amdgcn_mfma_f32_16x16x32_bf16(a0, b1[1][0], acc1, 0, 0, 0);
    acc0 = __builtin_amdgcn_mfma_f32_16x16x32_bf16(a1, b1[0][1], acc0, 0, 0, 0);
    acc1 = __builtin_amdgcn_mfma_f32_16x16x32_bf16(a1, b1[1][1], acc1, 0, 0, 0);
    acc0 = __builtin_amdgcn_mfma_f32_16x16x32_bf16(a2, b1[0][2], acc0, 0, 0, 0);
    acc1 = __builtin_amdgcn_mfma_f32_16x16x32_bf16(a2, b1[1][2], acc1, 0, 0, 0);

    unsigned short* myY = y1L[wid];
    #pragma unroll
    for (int r = 0; r < 4; ++r) {
        float v0 = acc0[r] + bias1a;
        float v1 = acc1[r] + bias1b;
        v0 = (v0 > 0.f) ? v0 : 0.01f * v0;
        v1 = (v1 > 0.f) ? v1 : 0.01f * v1;
        myY[(quad * 4 + r) * Y1_STRIDE + lm]      = f2bf(v0);
        myY[(quad * 4 + r) * Y1_STRIDE + 16 + lm] = f2bf(v1);
    }
    bf16x8 a2f = *(const bf16x8*)(myY + lm * Y1_STRIDE + quad * 8);
    f32x4v acc20 = (f32x4v){0.f, 0.f, 0.f, 0.f};
    f32x4v acc21 = acc20;
    acc20 = __builtin_amdgcn_mfma_f32_16x16x32_bf16(a2f, b2f[0], acc20, 0, 0, 0);
    acc21 = __builtin_amdgcn_mfma_f32_16x16x32_bf16(a2f, b2f[1], acc21, 0, 0, 0);

    float part[4];
    #pragma unroll
    for (int r = 0; r < 4; ++r) {
        float y2a = acc20[r] + bias2a;
        float y2b = acc21[r] + bias2b;
        y2a = (y2a > 0.f) ? y2a : 0.01f * y2a;
        y2b = (y2b > 0.f) ? y2b : 0.01f * y2b;
        part[r] = y2a * w3a + y2b * w3b;
    }
    #pragma unroll
    for (int st = 1; st < 16; st <<= 1) {
        #pragma unroll
        for (int r = 0; r < 4; ++r) part[r] += __shfl_xor(part[r], st, 64);
    }
    if (lm == 0) {
        #pragma unroll
        for (int r = 0; r < 4; ++r) {
            float a3 = part[r] + b3;
            conc[wid * 16 + quad * 4 + r] = (a3 > 20.f) ? a3 : log1pf(expf(a3));
        }
    }
    __syncthreads();

    int tid = threadIdx.x;
    float myabs = 0.f;
    if (tid < 96) {
        int gnode = nbase + tid;
        if (gnode < n) {
            int g0 = (tid / 6) * 6;
            float s = 0.f;
            #pragma unroll
            for (int i = 0; i < 6; ++i) s += conc[g0 + i];
            float c = conc[tid];
            out[gnode] = c / (s + 1e-20f);
            myabs = fabsf(c);
        }
    }
    #pragma unroll
    for (int off = 32; off > 0; off >>= 1) myabs += __shfl_down(myabs, off, 64);
    if (lane == 0) wsum[wid] = myabs;
    __syncthreads();
    if (tid == 0)
        partial[blockIdx.x] = wsum[0] + wsum[1] + wsum[2] + wsum[3] + wsum[4] + wsum[5];
}

// ---------------- final reduction of per-block partials ----------------
__global__ void reduce_reg(const float* __restrict__ partial, float* __restrict__ regptr, int nb) {
    __shared__ float wsum[4];
    int tid = threadIdx.x;
    float s = 0.f;
    for (int i = tid; i < nb; i += 256) s += partial[i];
    #pragma unroll
    for (int off = 32; off > 0; off >>= 1) s += __shfl_down(s, off, 64);
    if ((tid & 63) == 0) wsum[tid >> 6] = s;
    __syncthreads();
    if (tid == 0)
        *regptr = (wsum[0] + wsum[1] + wsum[2] + wsum[3]) * (1.0f / (float)N_NODES);
}

extern "C" void kernel_launch(void* const* d_in, const int* in_sizes, int n_in,
                              void* d_out, int out_size, void* d_ws, size_t ws_size,
                              hipStream_t stream) {
    const float* state = (const float*)d_in[0];
    const int*   ei    = (const int*)d_in[1];
    const float* convW = (const float*)d_in[2];
    const float* convb = (const float*)d_in[3];
    const float* gW1   = (const float*)d_in[4];
    const float* gb1   = (const float*)d_in[5];
    const float* gW2   = (const float*)d_in[6];
    const float* gb2   = (const float*)d_in[7];
    const float* l1W   = (const float*)d_in[8];
    const float* l1b   = (const float*)d_in[9];
    const float* l2W   = (const float*)d_in[10];
    const float* l2b   = (const float*)d_in[11];
    const float* l3W   = (const float*)d_in[12];
    const float* l3b   = (const float*)d_in[13];

    const int n = N_NODES, E = N_EDGES, B = B_ROWS;
    const int* src = ei;
    const int* dst = ei + E;

    // ---- workspace layout ----
    char* w = (char*)d_ws;
    int*   counts = (int*)w;                 w += NPAD * 4;
    int*   rank   = (int*)w;                 w += (size_t)E * 4;
    int*   rowptr = (int*)w;                 w += NPAD * 4;
    int*   bsum   = (int*)w;                 w += 256 * 4;
    float* dinv   = (float*)w;               w += NPAD * 4;
    int*   csr    = (int*)w;                 w += (size_t)E * 4;
    float* hregion= (float*)w;               w += (size_t)n * 64 * 4; // 38.4 MB
    unsigned short* xb  = (unsigned short*)w; w += (size_t)n * 64 * 2; // 19.2 MB
    unsigned short* y1b = (unsigned short*)w; w += (size_t)B_ROWS * 256 * 2; // 12.8 MB DEDICATED
    unsigned short* w1b = (unsigned short*)w; w += 98304 * 2;
    unsigned short* w1p = (unsigned short*)w; w += 3072 * 2;
    unsigned short* w2p = (unsigned short*)w; w += 1024 * 2;
    unsigned short* wcb = (unsigned short*)w; w += 4096 * 2;
    float* partial = (float*)w;              w += MLP_BLOCKS * 4;
    // hregion phases:
    //   phase 1 (k2,k3): hb = [0..19.2MB) bf16 h*dinv ; sb = [19.2..38.4MB) bf16 state
    //   after k3: xgb aliases hregion[0..0.8MB) (hb dead once k3 completes)
    unsigned short* hb  = (unsigned short*)hregion;
    unsigned short* sb  = (unsigned short*)(hregion + 4800000);
    unsigned short* xgb = (unsigned short*)hregion;

    float* out    = (float*)d_out;
    float* regptr = out + n;

    hipMemsetAsync(counts, 0, NPAD * 4, stream);

    k1_prep_degree<<<PREP_BLOCKS + DEGREE_BLOCKS, 256, 0, stream>>>(
        dst, counts, rank, convW, gW1, l1W, l2W, wcb, w1b, w1p, w2p, E);
    scan_block<<<NSCAN, 256, 0, stream>>>(counts, rowptr, bsum, n);
    scan_sums<<<1, 256, 0, stream>>>(bsum, NSCAN);
    scan_add<<<(n + 256) / 256, 256, 0, stream>>>(rowptr, bsum, counts, dinv, n, E);
    k2_conv_fill<<<CONV_BLOCKS + FILL_BLOCKS, 256, 0, stream>>>(
        state, wcb, dinv, hb, sb, src, dst, rowptr, rank, csr, n, E);
    k3_gemm1_gather<<<GEMM1_BLOCKS + GATHER_BLOCKS, 512, 0, stream>>>(
        sb, w1b, gb1, y1b, B, rowptr, csr, hb, dinv, convb, xb, n, E);
    global_gemm2<<<(B * 64 + 255) / 256, 256, 0, stream>>>(y1b, gW2, gb2, xgb, B);
    mlp_mfma<<<MLP_BLOCKS, 384, 0, stream>>>(xb, xgb, w1p, w2p, l1b, l2b, l3W, l3b,
                                             out, partial, n);
    reduce_reg<<<1, 256, 0, stream>>>(partial, regptr, MLP_BLOCKS);
}